// Round 4
// baseline (464.628 us; speedup 1.0000x reference)
//
#include <hip/hip_runtime.h>
#include <hip/hip_fp16.h>

typedef _Float16 half4v __attribute__((ext_vector_type(4)));
typedef _Float16 half8v __attribute__((ext_vector_type(8)));
typedef float floatx4 __attribute__((ext_vector_type(4)));

#define GLOBAL_AS __attribute__((address_space(1)))
#define LDS_AS __attribute__((address_space(3)))

__device__ __forceinline__ void async_copy16(const _Float16* g, _Float16* l) {
    __builtin_amdgcn_global_load_lds((const GLOBAL_AS unsigned int*)g,
                                     (LDS_AS unsigned int*)l, 16, 0, 0);
}

// Stage R x 64-half tile (global row stride ldg halves) into LDS (row stride 64,
// XOR chunk swizzle: slot (row,c) holds global chunk c^(row&7)).
template <int R>
__device__ __forceinline__ void stage_tile(const _Float16* g, long ldg,
                                           _Float16* lds, int wave, int lane) {
    const int rl = lane >> 3;
    const int gc = (lane & 7) ^ rl;
#pragma unroll
    for (int i = 0; i < (R >> 5); ++i) {
        const int br = wave * (R >> 2) + i * 8;
        async_copy16(g + (long)(br + rl) * ldg + gc * 8, lds + br * 64);
    }
}

// ---------------- convert f32 -> f16 ----------------
__global__ __launch_bounds__(256) void k_f32_to_f16(const float* __restrict__ in,
                                                    _Float16* __restrict__ out, int n) {
    int i = (blockIdx.x * 256 + threadIdx.x) * 4;
    if (i >= n) return;
    float4 v = *(const float4*)(in + i);
    half4v h;
    h[0] = (_Float16)v.x; h[1] = (_Float16)v.y; h[2] = (_Float16)v.z; h[3] = (_Float16)v.w;
    *(half4v*)(out + i) = h;
}

// ------------- transpose + convert: in[R][C] f32 -> out[C][R] f16 -------------
__global__ __launch_bounds__(256) void k_transpose_f16(const float* __restrict__ in,
                                                       _Float16* __restrict__ out,
                                                       int R, int C) {
    __shared__ float tile[32][33];
    int bc = blockIdx.x * 32;
    int br = blockIdx.y * 32;
    int tx = threadIdx.x & 31, ty = threadIdx.x >> 5;
#pragma unroll
    for (int i = 0; i < 32; i += 8)
        tile[ty + i][tx] = in[(size_t)(br + ty + i) * C + bc + tx];
    __syncthreads();
#pragma unroll
    for (int i = 0; i < 32; i += 8)
        out[(size_t)(bc + ty + i) * R + br + tx] = (_Float16)tile[tx][ty + i];
}

// ---------------- NT GEMM (projections): C[M,N] = A[M,K] @ B[N,K]^T, f16 out ----------------
__global__ __launch_bounds__(256) void k_gemm_nt(const _Float16* __restrict__ A,
                                                 const _Float16* __restrict__ B,
                                                 _Float16* __restrict__ C,
                                                 int M, int N, int K) {
    __shared__ __align__(16) _Float16 As[128 * 64];
    __shared__ __align__(16) _Float16 Bs[128 * 64];
    const int tid = threadIdx.x, lane = tid & 63, wave = tid >> 6;
    const int wm = (wave >> 1) * 64, wn = (wave & 1) * 64;
    const int quad = lane >> 4, lr = lane & 15;
    const long m0 = (long)blockIdx.y * 128, n0 = (long)blockIdx.x * 128;

    floatx4 acc[4][4] = {};
    for (int kt = 0; kt < K; kt += 64) {
        stage_tile<128>(A + m0 * K + kt, K, As, wave, lane);
        stage_tile<128>(B + n0 * K + kt, K, Bs, wave, lane);
        __syncthreads();
#pragma unroll
        for (int kk = 0; kk < 64; kk += 32) {
            const int sl = ((((kk >> 3) + quad) ^ (lr & 7)) * 8);
            half8v af[4], bf[4];
#pragma unroll
            for (int i = 0; i < 4; ++i) af[i] = *(const half8v*)&As[(wm + i * 16 + lr) * 64 + sl];
#pragma unroll
            for (int j = 0; j < 4; ++j) bf[j] = *(const half8v*)&Bs[(wn + j * 16 + lr) * 64 + sl];
#pragma unroll
            for (int i = 0; i < 4; ++i)
#pragma unroll
                for (int j = 0; j < 4; ++j)
                    acc[i][j] = __builtin_amdgcn_mfma_f32_16x16x32_f16(af[i], bf[j], acc[i][j], 0, 0, 0);
        }
        __syncthreads();
    }
#pragma unroll
    for (int i = 0; i < 4; ++i) {
        long rbase = m0 + wm + i * 16 + quad * 4;
#pragma unroll
        for (int j = 0; j < 4; ++j) {
            long col = n0 + wn + j * 16 + lr;
#pragma unroll
            for (int r = 0; r < 4; ++r)
                C[(rbase + r) * (long)N + col] = (_Float16)acc[i][j][r];
        }
    }
}

// ---------------- fused flash attention chunk kernel ----------------
// grid (8 n-chunks, 64 q-tiles). Block: 64 q-rows x 1024 keys -> partial O[64][256]
// (unnormalized, ref max m_z) + per-row m_z, l_z.  Waves 2x2: wr=row half (32),
// wc = col half (S: 64 cols / PV: 128 cols).
#define SCALE 0.04419417382415922f
__global__ __launch_bounds__(256, 2) void k_flash(const _Float16* __restrict__ qk,
                                                  const _Float16* __restrict__ keys,
                                                  const _Float16* __restrict__ yT,
                                                  const int* __restrict__ mask,
                                                  float* __restrict__ part,
                                                  float* __restrict__ ml) {
    __shared__ __align__(16) char smem[50176];
    _Float16* Qs = (_Float16*)smem;             // [64][64]   (phase A)
    _Float16* Ks = (_Float16*)(smem + 8192);    // [128][64]  (phase A)
    _Float16* Ps = (_Float16*)smem;             // [64][136]  (phase B/C)
    _Float16* Ys = (_Float16*)(smem + 17408);   // [256][64]  (phase C)
    __shared__ float s_max[2][64];
    __shared__ float s_sum[2][64];

    const int tid = threadIdx.x, lane = tid & 63, wave = tid >> 6;
    const int wr = wave >> 1, wc = wave & 1;
    const int quad = lane >> 4, lr = lane & 15;
    const int nc = blockIdx.x;            // n-chunk
    const int q0 = blockIdx.y * 64;
    const long n0 = (long)nc * 1024;

    floatx4 acc_o[2][8] = {};
    float m_reg[2][4], l_reg[2][4];
#pragma unroll
    for (int i = 0; i < 2; ++i)
#pragma unroll
        for (int r = 0; r < 4; ++r) { m_reg[i][r] = -3.0e38f; l_reg[i][r] = 0.f; }

    const _Float16* Qg = qk + (long)q0 * 512;

    for (int t = 0; t < 8; ++t) {
        const _Float16* Kg = keys + (n0 + t * 128) * 512;
        // ---- phase A: S = Q @ Kt^T  (64x128, K=512) ----
        floatx4 acc_s[2][4] = {};
        for (int kt = 0; kt < 512; kt += 64) {
            stage_tile<64>(Qg + kt, 512, Qs, wave, lane);
            stage_tile<128>(Kg + kt, 512, Ks, wave, lane);
            __syncthreads();
#pragma unroll
            for (int kk = 0; kk < 64; kk += 32) {
                const int sl = ((((kk >> 3) + quad) ^ (lr & 7)) * 8);
                half8v af[2], bf[4];
#pragma unroll
                for (int i = 0; i < 2; ++i)
                    af[i] = *(const half8v*)&Qs[(wr * 32 + i * 16 + lr) * 64 + sl];
#pragma unroll
                for (int j = 0; j < 4; ++j)
                    bf[j] = *(const half8v*)&Ks[(wc * 64 + j * 16 + lr) * 64 + sl];
#pragma unroll
                for (int i = 0; i < 2; ++i)
#pragma unroll
                    for (int j = 0; j < 4; ++j)
                        acc_s[i][j] = __builtin_amdgcn_mfma_f32_16x16x32_f16(af[i], bf[j], acc_s[i][j], 0, 0, 0);
            }
            __syncthreads();
        }
        // ---- phase B: mask + online softmax ----
        float val[2][4][4], rmax[2][4];
#pragma unroll
        for (int i = 0; i < 2; ++i)
#pragma unroll
            for (int r = 0; r < 4; ++r) rmax[i][r] = -3.0e38f;
#pragma unroll
        for (int i = 0; i < 2; ++i)
#pragma unroll
            for (int j = 0; j < 4; ++j) {
                const int col = wc * 64 + j * 16 + lr;
#pragma unroll
                for (int r = 0; r < 4; ++r) {
                    const int row = wr * 32 + i * 16 + quad * 4 + r;
                    const int mk = mask[(size_t)(q0 + row) * 8192 + n0 + t * 128 + col];
                    float v = (mk > 0) ? acc_s[i][j][r] * SCALE : -3.0e38f;
                    val[i][j][r] = v;
                    rmax[i][r] = fmaxf(rmax[i][r], v);
                }
            }
#pragma unroll
        for (int i = 0; i < 2; ++i)
#pragma unroll
            for (int r = 0; r < 4; ++r) {
#pragma unroll
                for (int m = 1; m < 16; m <<= 1)
                    rmax[i][r] = fmaxf(rmax[i][r], __shfl_xor(rmax[i][r], m, 64));
            }
        if (lr == 0) {
#pragma unroll
            for (int i = 0; i < 2; ++i)
#pragma unroll
                for (int r = 0; r < 4; ++r)
                    s_max[wc][wr * 32 + i * 16 + quad * 4 + r] = rmax[i][r];
        }
        __syncthreads();
        float mnew[2][4], alpha[2][4], rsum[2][4];
#pragma unroll
        for (int i = 0; i < 2; ++i)
#pragma unroll
            for (int r = 0; r < 4; ++r) {
                const int row = wr * 32 + i * 16 + quad * 4 + r;
                float mt = fmaxf(s_max[0][row], s_max[1][row]);
                mnew[i][r] = fmaxf(m_reg[i][r], mt);
                alpha[i][r] = __expf(m_reg[i][r] - mnew[i][r]);
                m_reg[i][r] = mnew[i][r];
                rsum[i][r] = 0.f;
            }
#pragma unroll
        for (int i = 0; i < 2; ++i)
#pragma unroll
            for (int j = 0; j < 4; ++j) {
                const int col = wc * 64 + j * 16 + lr;
#pragma unroll
                for (int r = 0; r < 4; ++r) {
                    const int row = wr * 32 + i * 16 + quad * 4 + r;
                    float p = (val[i][j][r] > -1.0e37f) ? __expf(val[i][j][r] - mnew[i][r]) : 0.f;
                    rsum[i][r] += p;
                    Ps[row * 136 + col] = (_Float16)p;
                }
            }
#pragma unroll
        for (int i = 0; i < 2; ++i)
#pragma unroll
            for (int j = 0; j < 8; ++j)
#pragma unroll
                for (int r = 0; r < 4; ++r) acc_o[i][j][r] *= alpha[i][r];
#pragma unroll
        for (int i = 0; i < 2; ++i)
#pragma unroll
            for (int r = 0; r < 4; ++r) {
#pragma unroll
                for (int m = 1; m < 16; m <<= 1)
                    rsum[i][r] += __shfl_xor(rsum[i][r], m, 64);
            }
        if (lr == 0) {
#pragma unroll
            for (int i = 0; i < 2; ++i)
#pragma unroll
                for (int r = 0; r < 4; ++r)
                    s_sum[wc][wr * 32 + i * 16 + quad * 4 + r] = rsum[i][r];
        }
        __syncthreads();
#pragma unroll
        for (int i = 0; i < 2; ++i)
#pragma unroll
            for (int r = 0; r < 4; ++r) {
                const int row = wr * 32 + i * 16 + quad * 4 + r;
                l_reg[i][r] = l_reg[i][r] * alpha[i][r] + s_sum[0][row] + s_sum[1][row];
            }
        // ---- phase C: O += P @ Yt ----
        const _Float16* Yg = yT + n0 + t * 128;
#pragma unroll
        for (int kk2 = 0; kk2 < 128; kk2 += 64) {
            stage_tile<256>(Yg + kk2, 8192, Ys, wave, lane);
            __syncthreads();
#pragma unroll
            for (int kkk = 0; kkk < 64; kkk += 32) {
                const int sl = ((((kkk >> 3) + quad) ^ (lr & 7)) * 8);
                half8v pa[2];
#pragma unroll
                for (int i = 0; i < 2; ++i)
                    pa[i] = *(const half8v*)&Ps[(wr * 32 + i * 16 + lr) * 136 + kk2 + kkk + quad * 8];
#pragma unroll
                for (int j = 0; j < 8; ++j) {
                    half8v yb = *(const half8v*)&Ys[(wc * 128 + j * 16 + lr) * 64 + sl];
                    acc_o[0][j] = __builtin_amdgcn_mfma_f32_16x16x32_f16(pa[0], yb, acc_o[0][j], 0, 0, 0);
                    acc_o[1][j] = __builtin_amdgcn_mfma_f32_16x16x32_f16(pa[1], yb, acc_o[1][j], 0, 0, 0);
                }
            }
            __syncthreads();
        }
    }
    // ---- epilogue: partial O + m/l ----
    float* op = part + ((size_t)nc * 4096 + q0) * 256;
#pragma unroll
    for (int i = 0; i < 2; ++i)
#pragma unroll
        for (int j = 0; j < 8; ++j) {
            const int col = wc * 128 + j * 16 + lr;
#pragma unroll
            for (int r = 0; r < 4; ++r) {
                const int row = wr * 32 + i * 16 + quad * 4 + r;
                op[(long)row * 256 + col] = acc_o[i][j][r];
            }
        }
    if (wc == 0 && lr == 0) {
#pragma unroll
        for (int i = 0; i < 2; ++i)
#pragma unroll
            for (int r = 0; r < 4; ++r) {
                const int row = wr * 32 + i * 16 + quad * 4 + r;
                ml[(size_t)nc * 4096 + q0 + row] = m_reg[i][r];
                ml[32768 + (size_t)nc * 4096 + q0 + row] = l_reg[i][r];
            }
    }
}

// ---------------- combine 8 chunk partials with softmax merge ----------------
__global__ __launch_bounds__(256) void k_combine(const float* __restrict__ part,
                                                 const float* __restrict__ ml,
                                                 float* __restrict__ out) {
    const int q = blockIdx.x * 4 + (threadIdx.x >> 6);
    const int c = (threadIdx.x & 63) * 4;
    float mz[8], lz[8], M = -3.0e38f;
#pragma unroll
    for (int z = 0; z < 8; ++z) {
        mz[z] = ml[(size_t)z * 4096 + q];
        lz[z] = ml[32768 + (size_t)z * 4096 + q];
        M = fmaxf(M, mz[z]);
    }
    float L = 0.f;
    float4 o = make_float4(0.f, 0.f, 0.f, 0.f);
#pragma unroll
    for (int z = 0; z < 8; ++z) {
        float w = __expf(mz[z] - M);
        L += w * lz[z];
        float4 v = *(const float4*)(part + ((size_t)z * 4096 + q) * 256 + c);
        o.x += w * v.x; o.y += w * v.y; o.z += w * v.z; o.w += w * v.w;
    }
    float inv = (L > 0.f) ? 1.f / L : 0.f;
    o.x *= inv; o.y *= inv; o.z *= inv; o.w *= inv;
    *(float4*)(out + (size_t)q * 256 + c) = o;
}

extern "C" void kernel_launch(void* const* d_in, const int* in_sizes, int n_in,
                              void* d_out, int out_size, void* d_ws, size_t ws_size,
                              hipStream_t stream) {
    const float* search_x = (const float*)d_in[0];  // [8192,1024]
    const float* search_y = (const float*)d_in[1];  // [8192,256]
    const float* query_x  = (const float*)d_in[2];  // [4096,1024]
    const int*   mask     = (const int*)d_in[3];    // [4096,8192]
    const float* Wk       = (const float*)d_in[4];  // [1024,512]
    const float* Wq       = (const float*)d_in[5];  // [1024,512]
    (void)in_sizes; (void)n_in; (void)ws_size; (void)out_size;

    char* p = (char*)d_ws;
    _Float16* xh   = (_Float16*)p; p += (size_t)8192 * 1024 * 2;
    _Float16* qh   = (_Float16*)p; p += (size_t)4096 * 1024 * 2;
    _Float16* wkT  = (_Float16*)p; p += (size_t)512 * 1024 * 2;
    _Float16* wqT  = (_Float16*)p; p += (size_t)512 * 1024 * 2;
    _Float16* yT   = (_Float16*)p; p += (size_t)256 * 8192 * 2;
    _Float16* keys = (_Float16*)p; p += (size_t)8192 * 512 * 2;
    _Float16* qk   = (_Float16*)p; p += (size_t)4096 * 512 * 2;
    float*    part = (float*)p;    p += (size_t)8 * 4096 * 256 * 4;
    float*    ml   = (float*)p;    p += (size_t)2 * 8 * 4096 * 4;

    k_f32_to_f16<<<8192, 256, 0, stream>>>(search_x, xh, 8192 * 1024);
    k_f32_to_f16<<<4096, 256, 0, stream>>>(query_x, qh, 4096 * 1024);
    k_transpose_f16<<<dim3(16, 32), 256, 0, stream>>>(Wk, wkT, 1024, 512);
    k_transpose_f16<<<dim3(16, 32), 256, 0, stream>>>(Wq, wqT, 1024, 512);
    k_transpose_f16<<<dim3(8, 256), 256, 0, stream>>>(search_y, yT, 8192, 256);

    k_gemm_nt<<<dim3(4, 64), 256, 0, stream>>>(xh, wkT, keys, 8192, 512, 1024);
    k_gemm_nt<<<dim3(4, 32), 256, 0, stream>>>(qh, wqT, qk, 4096, 512, 1024);

    k_flash<<<dim3(8, 64), 256, 0, stream>>>(qk, keys, yT, mask, part, ml);
    k_combine<<<1024, 256, 0, stream>>>(part, ml, (float*)d_out);
}